// Round 7
// baseline (441.871 us; speedup 1.0000x reference)
//
#include <hip/hip_runtime.h>
#include <hip/hip_bf16.h>

// LocalAggregation: B=8, N=2048, K=32, D=64, C1=64, C2=128, R=0.15, EPS=1e-5
// f32 storage, bf16-ified values.
// R7: factored stats1 — no h1 gather pass.
//   h1[row,c] = g[m,c] + dx*wx[c]+dy*wy[c]+dz*wz[c],  g = feat @ W1[3:]
//   sum1[c]   = SUM_m cnt[m] g[m,c] + wx M1x + wy M1y + wz M1z
//   sumsq1[c] = SUM_m cnt g^2 + 2(wx A3x + wy A3y + wz A3z)
//               + wx^2 Mxx + wy^2 Myy + wz^2 Mzz + 2(wxwy Mxy + wxwz Mxz + wywz Myz)
//   cnt/DX/DY/DZ[m] + 9 global moments accumulated in k1 (ball query);
//   A-sums accumulated in kB (which computes g anyway).
// kD applies BN1 inline (sc1/sh1 from kS), MFMA h2, stats2 + pre-BN max-pool.
// gamma2>0 => relu(bn2(.)) monotone => max-pool commutes with bn2+relu (k5).

#define BB 8
#define NN 2048
#define KK 32
#define DD 64
#define CC1 64
#define CC2 128
#define TOTROWS (BB*NN*KK) // 524288
#define SITES (BB*NN)      // 16384

typedef __bf16 bf16x8 __attribute__((ext_vector_type(8)));
typedef float  f32x4  __attribute__((ext_vector_type(4)));

__device__ __forceinline__ float rl(float v, int l) {
  return __int_as_float(__builtin_amdgcn_readlane(__float_as_int(v), l));
}

// ---------------- K1: ball query + per-m scatter + global moments ----------------
// 512 blocks x 256 thr; block = (batch, 32-query group), wave = 8 queries.
// Selector arithmetic identical to the round-4/6 PASSING version.
__global__ __launch_bounds__(256) void k1_ball(const float* __restrict__ pos,
                                               int* __restrict__ idx,
                                               float* __restrict__ cnt,
                                               float* __restrict__ DXa,
                                               float* __restrict__ DYa,
                                               float* __restrict__ DZa,
                                               float* __restrict__ mom)
{
  __shared__ float4 P[NN];  // 32 KB: x,y,z,S
  const int b = blockIdx.x >> 6;
  const int qbase = (blockIdx.x & 63) * 32;
  for (int i = threadIdx.x; i < NN; i += 256) {
    const float* p = pos + ((size_t)b*NN + i)*3;
    float x = p[0], y = p[1], z = p[2];
    float s = __fadd_rn(__fadd_rn(__fmul_rn(x,x), __fmul_rn(y,y)), __fmul_rn(z,z));
    P[i] = make_float4(x, y, z, s);
  }
  __syncthreads();
  const int wave = threadIdx.x >> 6, lane = threadIdx.x & 63;
  const float R2 = (float)(0.15 * 0.15);
  const unsigned long long lt = (lane == 63) ? 0x7fffffffffffffffull
                                             : ((1ull << lane) - 1ull);
  float m1x=0.f,m1y=0.f,m1z=0.f,mxx=0.f,myy=0.f,mzz=0.f,mxy=0.f,mxz=0.f,myz=0.f;
  for (int qi = wave; qi < 32; qi += 4) {
    const int q = qbase + qi;
    const float4 Q = P[q];
    int* ip = idx + ((size_t)b*NN + q)*KK;
    int cn = 0, first = -1;
    for (int step = 0; step < 32; ++step) {
      float4 p = P[step*64 + lane];
      float d = __fmul_rn(Q.x, p.x);
      d = fmaf(Q.y, p.y, d);
      d = fmaf(Q.z, p.z, d);
      float sq = __fsub_rn(__fadd_rn(Q.w, p.w), __fmul_rn(2.0f, d));
      bool in = !(sq > R2);
      unsigned long long mask = __ballot(in);
      if (first < 0 && mask) first = step*64 + (int)__builtin_ctzll(mask);
      int dst = cn + (int)__popcll(mask & lt);
      if (in && dst < KK) {
        ip[dst] = step*64 + lane;
        float dx = p.x - Q.x, dy = p.y - Q.y, dz = p.z - Q.z;
        int bm = b*NN + step*64 + lane;
        atomicAdd(&cnt[bm], 1.0f);
        atomicAdd(&DXa[bm], dx);
        atomicAdd(&DYa[bm], dy);
        atomicAdd(&DZa[bm], dz);
        m1x += dx; m1y += dy; m1z += dz;
        mxx = fmaf(dx,dx,mxx); myy = fmaf(dy,dy,myy); mzz = fmaf(dz,dz,mzz);
        mxy = fmaf(dx,dy,mxy); mxz = fmaf(dx,dz,mxz); myz = fmaf(dy,dz,myz);
      }
      cn += (int)__popcll(mask);
      if (cn >= KK) break;
    }
    if (lane >= cn && lane < KK) ip[lane] = first;  // cn>=1 (self in ball)
    int wt = KK - cn;
    if (wt > 0 && lane == 0) {   // padding rows: (KK-cn) copies of 'first'
      float4 pf = P[first];
      float dx = pf.x - Q.x, dy = pf.y - Q.y, dz = pf.z - Q.z;
      float w = (float)wt;
      int bm = b*NN + first;
      atomicAdd(&cnt[bm], w);
      atomicAdd(&DXa[bm], w*dx);
      atomicAdd(&DYa[bm], w*dy);
      atomicAdd(&DZa[bm], w*dz);
      m1x += w*dx; m1y += w*dy; m1z += w*dz;
      mxx = fmaf(w*dx,dx,mxx); myy = fmaf(w*dy,dy,myy); mzz = fmaf(w*dz,dz,mzz);
      mxy = fmaf(w*dx,dy,mxy); mxz = fmaf(w*dx,dz,mxz); myz = fmaf(w*dy,dz,myz);
    }
  }
  float vals[9] = {m1x,m1y,m1z,mxx,myy,mzz,mxy,mxz,myz};
  #pragma unroll
  for (int i = 0; i < 9; ++i) {
    float v = vals[i];
    #pragma unroll
    for (int s = 1; s < 64; s <<= 1) v += __shfl_xor(v, s, 64);
    if (lane == 0) atomicAdd(&mom[i], v);
  }
}

// ---------------- KB: g = feat @ W1[3:] and A-sums ----------------
// 256 blocks -> 1024 waves x 16 rows. lane = c1 channel.
// A layout: [0:64) Sum cnt*g, [64:128) Sum cnt*g^2, [128:192) Sum g*DX,
//           [192:256) Sum g*DY, [256:320) Sum g*DZ
__global__ __launch_bounds__(256) void kB_g(const float* __restrict__ feat,
                                            const float* __restrict__ W1,
                                            const float* __restrict__ cnt,
                                            const float* __restrict__ DXa,
                                            const float* __restrict__ DYa,
                                            const float* __restrict__ DZa,
                                            float* __restrict__ g,
                                            float* __restrict__ A)
{
  __shared__ float red[320];
  for (int i = threadIdx.x; i < 320; i += 256) red[i] = 0.f;
  __syncthreads();
  const int lane = threadIdx.x & 63;
  const int gw = (blockIdx.x*256 + threadIdx.x) >> 6;
  float wf[DD];
  #pragma unroll
  for (int d = 0; d < DD; ++d) wf[d] = W1[(3+d)*CC1 + lane];
  float a1=0.f, a2=0.f, a3=0.f, a4=0.f, a5=0.f;
  for (int r = 0; r < 16; ++r) {
    int row = gw*16 + r;
    float f = feat[(size_t)row*DD + lane];
    float h0 = 0.f, h1 = 0.f, h2 = 0.f, h3 = 0.f;
    #pragma unroll
    for (int j = 0; j < 64; j += 4) {
      h0 = fmaf(rl(f, j  ), wf[j  ], h0);
      h1 = fmaf(rl(f, j+1), wf[j+1], h1);
      h2 = fmaf(rl(f, j+2), wf[j+2], h2);
      h3 = fmaf(rl(f, j+3), wf[j+3], h3);
    }
    float h = (h0+h1) + (h2+h3);
    g[(size_t)row*CC1 + lane] = h;
    float c = cnt[row], dxs = DXa[row], dys = DYa[row], dzs = DZa[row];
    float ch = c*h;
    a1 += ch; a2 = fmaf(ch, h, a2);
    a3 = fmaf(h, dxs, a3); a4 = fmaf(h, dys, a4); a5 = fmaf(h, dzs, a5);
  }
  atomicAdd(&red[lane], a1);
  atomicAdd(&red[64+lane], a2);
  atomicAdd(&red[128+lane], a3);
  atomicAdd(&red[192+lane], a4);
  atomicAdd(&red[256+lane], a5);
  __syncthreads();
  for (int i = threadIdx.x; i < 320; i += 256) atomicAdd(&A[i], red[i]);
}

// ---------------- KS: assemble stats1 -> sc1, sh1, W1s ----------------
__global__ __launch_bounds__(256) void kS_fold(
    const float* __restrict__ W1, const float* __restrict__ gamma1,
    const float* __restrict__ beta1, const float* __restrict__ A,
    const float* __restrict__ mom,
    float* __restrict__ sc1, float* __restrict__ sh1, float* __restrict__ W1s)
{
  int c = threadIdx.x;
  if (c >= CC1) return;
  float wx = W1[c], wy = W1[CC1+c], wz = W1[2*CC1+c];
  float A1 = A[c], A2 = A[64+c], A3x = A[128+c], A3y = A[192+c], A3z = A[256+c];
  float sum1 = A1 + wx*mom[0] + wy*mom[1] + wz*mom[2];
  float ss = A2 + 2.f*(wx*A3x + wy*A3y + wz*A3z)
           + wx*wx*mom[3] + wy*wy*mom[4] + wz*wz*mom[5]
           + 2.f*(wx*wy*mom[6] + wx*wz*mom[7] + wy*wz*mom[8]);
  const float invN = 1.0f / (float)TOTROWS;
  float mean = sum1 * invN;
  float var  = ss * invN - mean*mean;
  float sc = rsqrtf(var + 1e-5f) * gamma1[c];
  float sh = beta1[c] - mean * sc;
  sc1[c] = sc; sh1[c] = sh;
  W1s[c] = wx*sc; W1s[64+c] = wy*sc; W1s[128+c] = wz*sc;
}

// ---------------- KD: MFMA main pass (BN1 inline) ----------------
// 1024 blocks -> 4096 waves x 4 sites. Per site A1(32x64 bf16) @ W2(64x128).
// a = relu(g*sc + dx*wxs + dy*wys + dz*wzs + sh).
// A-frag: lane holds A[m=lane&15][k=quad*8+j]; B-frag: B[k=quad*8+j][n=lane&15];
// C/D: col=lane&15, row=quad*4+reg (m89-verified).
__global__ __launch_bounds__(256, 2) void kD_mfma(
    const float* __restrict__ pos, const int* __restrict__ idx,
    const float* __restrict__ g, const float* __restrict__ sc1,
    const float* __restrict__ sh1, const float* __restrict__ W1s,
    const float* __restrict__ W2,
    float* __restrict__ stats2, float* __restrict__ out_nf)
{
  __shared__ float red2[256];
  for (int i = threadIdx.x; i < 256; i += 256) red2[i] = 0.f;
  __syncthreads();
  const int lane = threadIdx.x & 63;
  const int quad = lane >> 4;
  const int col  = lane & 15;
  const int gw = (blockIdx.x*256 + threadIdx.x) >> 6;

  bf16x8 Bf[2][8];
  #pragma unroll
  for (int kt = 0; kt < 2; ++kt)
    #pragma unroll
    for (int nt = 0; nt < 8; ++nt) {
      bf16x8 v;
      #pragma unroll
      for (int j = 0; j < 8; ++j)
        v[j] = (__bf16)W2[(kt*32 + quad*8 + j)*CC2 + nt*16 + col];
      Bf[kt][nt] = v;
    }
  float wxs[2][8], wys[2][8], wzs[2][8], scj[2][8], shj[2][8];
  #pragma unroll
  for (int kt = 0; kt < 2; ++kt)
    #pragma unroll
    for (int j = 0; j < 8; ++j) {
      int c = kt*32 + quad*8 + j;
      wxs[kt][j] = W1s[c]; wys[kt][j] = W1s[64+c]; wzs[kt][j] = W1s[128+c];
      scj[kt][j] = sc1[c]; shj[kt][j] = sh1[c];
    }
  float ssum[8], ssq[8];
  #pragma unroll
  for (int nt = 0; nt < 8; ++nt) { ssum[nt] = 0.f; ssq[nt] = 0.f; }

  for (int si = 0; si < 4; ++si) {
    const int site = gw*4 + si;
    const int b = site >> 11;
    const float* pc = pos + (size_t)site*3;
    const float cx = pc[0], cy = pc[1], cz = pc[2];
    int mm[2]; float dx[2], dy[2], dz[2];
    #pragma unroll
    for (int mt = 0; mt < 2; ++mt) {
      mm[mt] = idx[site*KK + mt*16 + col];
      const float* pm = pos + ((size_t)b*NN + mm[mt])*3;
      dx[mt] = pm[0]-cx; dy[mt] = pm[1]-cy; dz[mt] = pm[2]-cz;
    }
    bf16x8 Af[2][2];
    #pragma unroll
    for (int mt = 0; mt < 2; ++mt)
      #pragma unroll
      for (int kt = 0; kt < 2; ++kt) {
        const float4* gp =
          (const float4*)(g + (((size_t)b*NN + mm[mt])*CC1 + kt*32 + quad*8));
        float4 g0 = gp[0], g1 = gp[1];
        float hv[8] = {g0.x,g0.y,g0.z,g0.w,g1.x,g1.y,g1.z,g1.w};
        bf16x8 v;
        #pragma unroll
        for (int j = 0; j < 8; ++j) {
          float t = fmaf(dz[mt], wzs[kt][j],
                    fmaf(dy[mt], wys[kt][j],
                    fmaf(dx[mt], wxs[kt][j], shj[kt][j])));
          float h = fmaf(hv[j], scj[kt][j], t);
          v[j] = (__bf16)fmaxf(h, 0.f);
        }
        Af[mt][kt] = v;
      }
    float mx[8];
    #pragma unroll
    for (int nt = 0; nt < 8; ++nt) mx[nt] = -3.0e38f;
    #pragma unroll
    for (int mt = 0; mt < 2; ++mt) {
      f32x4 acc[8];
      #pragma unroll
      for (int nt = 0; nt < 8; ++nt) {
        f32x4 a = {0.f, 0.f, 0.f, 0.f};
        a = __builtin_amdgcn_mfma_f32_16x16x32_bf16(Af[mt][0], Bf[0][nt], a, 0, 0, 0);
        a = __builtin_amdgcn_mfma_f32_16x16x32_bf16(Af[mt][1], Bf[1][nt], a, 0, 0, 0);
        acc[nt] = a;
      }
      #pragma unroll
      for (int nt = 0; nt < 8; ++nt)
        #pragma unroll
        for (int r = 0; r < 4; ++r) {
          float v = acc[nt][r];
          ssum[nt] += v; ssq[nt] = fmaf(v, v, ssq[nt]);
          mx[nt] = fmaxf(mx[nt], v);
        }
    }
    #pragma unroll
    for (int nt = 0; nt < 8; ++nt) {
      float m = mx[nt];
      m = fmaxf(m, __shfl_xor(m, 16, 64));
      m = fmaxf(m, __shfl_xor(m, 32, 64));
      if ((nt & 3) == quad)
        out_nf[(size_t)site*CC2 + nt*16 + col] = m;   // pre-BN pooled
    }
  }
  #pragma unroll
  for (int nt = 0; nt < 8; ++nt) {
    float s = ssum[nt];
    s += __shfl_xor(s, 16, 64); s += __shfl_xor(s, 32, 64);
    float q = ssq[nt];
    q += __shfl_xor(q, 16, 64); q += __shfl_xor(q, 32, 64);
    if (lane < 16) {
      atomicAdd(&red2[nt*16 + col], s);
      atomicAdd(&red2[128 + nt*16 + col], q);
    }
  }
  __syncthreads();
  atomicAdd(&stats2[threadIdx.x], red2[threadIdx.x]);
}

// ---------------- K4: position pass-through ----------------
__global__ __launch_bounds__(256) void k4_pos(const float* __restrict__ pos,
                                              float* __restrict__ out) {
  int i = blockIdx.x*256 + threadIdx.x;
  out[i] = pos[i];
}

// ---------------- K5: bn2 + relu in place on pooled ----------------
__global__ __launch_bounds__(256) void k5_bn2(const float* __restrict__ g2,
                                              const float* __restrict__ be2,
                                              const float* __restrict__ stats2,
                                              float* __restrict__ out_nf) {
  int i = blockIdx.x*256 + threadIdx.x;
  int c = i & (CC2-1);
  const float invc = 1.0f / (float)TOTROWS;
  float mean = stats2[c] * invc;
  float var  = stats2[128 + c] * invc - mean*mean;
  float sc = rsqrtf(var + 1e-5f) * g2[c];
  float sh = be2[c] - mean * sc;
  float x = out_nf[i];
  out_nf[i] = fmaxf(fmaf(x, sc, sh), 0.f);
}

extern "C" void kernel_launch(void* const* d_in, const int* in_sizes, int n_in,
                              void* d_out, int out_size, void* d_ws, size_t ws_size,
                              hipStream_t stream) {
  const float* pos  = (const float*)d_in[0];
  const float* feat = (const float*)d_in[1];
  const float* W1   = (const float*)d_in[2];
  const float* g1   = (const float*)d_in[3];
  const float* be1  = (const float*)d_in[4];
  const float* W2   = (const float*)d_in[5];
  const float* g2   = (const float*)d_in[6];
  const float* be2  = (const float*)d_in[7];
  float* out = (float*)d_out;
  float* out_nf = out + (size_t)BB*NN*3;

  char* w = (char*)d_ws;
  int*   idx    = (int*)w;                   // 2 MB
  float* cnt    = (float*)(w + 0x200000);    // 16384
  float* DXa    = cnt + SITES;
  float* DYa    = DXa + SITES;
  float* DZa    = DYa + SITES;
  float* A      = DZa + SITES;               // 320
  float* mom    = A + 320;                   // 9 (pad to 16)
  float* stats2 = mom + 16;                  // 256
  float* sc1    = stats2 + 256;              // 64
  float* sh1    = sc1 + 64;                  // 64
  float* W1s    = sh1 + 64;                  // 192
  float* g      = (float*)(w + 0x200000 + 0x50000);  // 4 MB

  // zero cnt..stats2 (4*16384 + 320 + 16 + 256 floats)
  hipMemsetAsync(cnt, 0, (4*SITES + 320 + 16 + 256)*sizeof(float), stream);
  k1_ball<<<512, 256, 0, stream>>>(pos, idx, cnt, DXa, DYa, DZa, mom);
  kB_g   <<<256, 256, 0, stream>>>(feat, W1, cnt, DXa, DYa, DZa, g, A);
  kS_fold<<<1, 256, 0, stream>>>(W1, g1, be1, A, mom, sc1, sh1, W1s);
  kD_mfma<<<1024, 256, 0, stream>>>(pos, idx, g, sc1, sh1, W1s, W2,
                                    stats2, out_nf);
  k4_pos <<<(BB*NN*3)/256, 256, 0, stream>>>(pos, out);
  k5_bn2 <<<(SITES*CC2)/256, 256, 0, stream>>>(g2, be2, stats2, out_nf);
}

// Round 8
// 275.689 us; speedup vs baseline: 1.6028x; 1.6028x over previous
//
#include <hip/hip_runtime.h>
#include <hip/hip_bf16.h>

// LocalAggregation: B=8, N=2048, K=32, D=64, C1=64, C2=128, R=0.15, EPS=1e-5
// f32 storage, bf16-ified values.
// Factored stats1 (validated R7):
//   h1[row,c] = g[m,c] + dx*wx[c]+dy*wy[c]+dz*wz[c],  g = feat @ W1[3:]
//   sum1[c]   = SUM_m cnt[m] g[m,c] + wx M1x + wy M1y + wz M1z
//   sumsq1[c] = SUM_m cnt g^2 + 2(wx A3x + wy A3y + wz A3z)
//               + wx^2 Mxx + wy^2 Myy + wz^2 Mzz + 2(wxwy Mxy + wxwz Mxz + wywz Myz)
// R8: scatter (cnt/DX/DY/DZ/moments) moved out of k1 into kP_scatter with
// per-batch LDS accumulators + coalesced unsafeAtomicAdd flush (R7's per-pair
// global atomics cost 300 us). Padding rows covered naturally via idx.
// kD applies BN1 inline, MFMA h2, stats2 + pre-BN max-pool.
// gamma2>0 => relu(bn2(.)) monotone => max-pool commutes with bn2+relu (k5).

#define BB 8
#define NN 2048
#define KK 32
#define DD 64
#define CC1 64
#define CC2 128
#define TOTROWS (BB*NN*KK) // 524288
#define SITES (BB*NN)      // 16384

typedef __bf16 bf16x8 __attribute__((ext_vector_type(8)));
typedef float  f32x4  __attribute__((ext_vector_type(4)));

__device__ __forceinline__ float rl(float v, int l) {
  return __int_as_float(__builtin_amdgcn_readlane(__float_as_int(v), l));
}

// ---------------- K1: ball query, ballot compaction (round-6 version) ----------------
// 512 blocks x 256 thr; block = (batch, 32-query group), wave = 8 queries.
__global__ __launch_bounds__(256) void k1_ball(const float* __restrict__ pos,
                                               int* __restrict__ idx)
{
  __shared__ float4 P[NN];  // 32 KB: x,y,z,S
  const int b = blockIdx.x >> 6;
  const int qbase = (blockIdx.x & 63) * 32;
  for (int i = threadIdx.x; i < NN; i += 256) {
    const float* p = pos + ((size_t)b*NN + i)*3;
    float x = p[0], y = p[1], z = p[2];
    float s = __fadd_rn(__fadd_rn(__fmul_rn(x,x), __fmul_rn(y,y)), __fmul_rn(z,z));
    P[i] = make_float4(x, y, z, s);
  }
  __syncthreads();
  const int wave = threadIdx.x >> 6, lane = threadIdx.x & 63;
  const float R2 = (float)(0.15 * 0.15);
  const unsigned long long lt = (lane == 63) ? 0x7fffffffffffffffull
                                             : ((1ull << lane) - 1ull);
  for (int qi = wave; qi < 32; qi += 4) {
    const int q = qbase + qi;
    const float4 Q = P[q];
    int* ip = idx + ((size_t)b*NN + q)*KK;
    int cnt = 0, first = -1;
    for (int step = 0; step < 32; ++step) {
      float4 p = P[step*64 + lane];
      float d = __fmul_rn(Q.x, p.x);
      d = fmaf(Q.y, p.y, d);
      d = fmaf(Q.z, p.z, d);
      float sq = __fsub_rn(__fadd_rn(Q.w, p.w), __fmul_rn(2.0f, d));
      bool in = !(sq > R2);
      unsigned long long mask = __ballot(in);
      if (first < 0 && mask) first = step*64 + (int)__builtin_ctzll(mask);
      int dst = cnt + (int)__popcll(mask & lt);
      if (in && dst < KK) ip[dst] = step*64 + lane;
      cnt += (int)__popcll(mask);
      if (cnt >= KK) break;
    }
    if (lane >= cnt && lane < KK) ip[lane] = first;  // cnt>=1 (self in ball)
  }
}

// ---------------- KP: per-m scatter + global moments, LDS-accumulated ----------------
// 128 blocks x 256 thr; block = (batch, 128-site slice). All pairs (incl.
// padding duplicates) iterated via idx — matches reference BN row population.
__global__ __launch_bounds__(256) void kP_scatter(
    const float* __restrict__ pos, const int* __restrict__ idx,
    float* __restrict__ cnt, float* __restrict__ DXa,
    float* __restrict__ DYa, float* __restrict__ DZa,
    float* __restrict__ mom)
{
  __shared__ float Px[NN], Py[NN], Pz[NN];          // 24 KB
  __shared__ float Sc[NN], Sx[NN], Sy[NN], Sz[NN];  // 32 KB
  const int b = blockIdx.x >> 4;
  const int slice = blockIdx.x & 15;   // 128 sites
  for (int i = threadIdx.x; i < NN; i += 256) {
    const float* p = pos + ((size_t)b*NN + i)*3;
    Px[i] = p[0]; Py[i] = p[1]; Pz[i] = p[2];
    Sc[i] = 0.f; Sx[i] = 0.f; Sy[i] = 0.f; Sz[i] = 0.f;
  }
  __syncthreads();
  const int* ip = idx + ((size_t)(b*NN + slice*128))*KK;
  float m1x=0.f,m1y=0.f,m1z=0.f,mxx=0.f,myy=0.f,mzz=0.f,mxy=0.f,mxz=0.f,myz=0.f;
  #pragma unroll 4
  for (int it = 0; it < 16; ++it) {    // 128*32 = 4096 pairs / 256 thr
    int flat = it*256 + threadIdx.x;
    int m  = ip[flat];
    int cs = slice*128 + (flat >> 5);
    float dx = Px[m]-Px[cs], dy = Py[m]-Py[cs], dz = Pz[m]-Pz[cs];
    atomicAdd(&Sc[m], 1.0f);
    atomicAdd(&Sx[m], dx);
    atomicAdd(&Sy[m], dy);
    atomicAdd(&Sz[m], dz);
    m1x += dx; m1y += dy; m1z += dz;
    mxx = fmaf(dx,dx,mxx); myy = fmaf(dy,dy,myy); mzz = fmaf(dz,dz,mzz);
    mxy = fmaf(dx,dy,mxy); mxz = fmaf(dx,dz,mxz); myz = fmaf(dy,dz,myz);
  }
  __syncthreads();
  for (int i = threadIdx.x; i < NN; i += 256) {
    unsafeAtomicAdd(&cnt[b*NN + i], Sc[i]);
    unsafeAtomicAdd(&DXa[b*NN + i], Sx[i]);
    unsafeAtomicAdd(&DYa[b*NN + i], Sy[i]);
    unsafeAtomicAdd(&DZa[b*NN + i], Sz[i]);
  }
  const int lane = threadIdx.x & 63;
  float vals[9] = {m1x,m1y,m1z,mxx,myy,mzz,mxy,mxz,myz};
  #pragma unroll
  for (int i = 0; i < 9; ++i) {
    float v = vals[i];
    #pragma unroll
    for (int s = 1; s < 64; s <<= 1) v += __shfl_xor(v, s, 64);
    if (lane == 0) unsafeAtomicAdd(&mom[i], v);
  }
}

// ---------------- KB: g = feat @ W1[3:] and A-sums ----------------
// 256 blocks -> 1024 waves x 16 rows. lane = c1 channel.
// A layout: [0:64) Sum cnt*g, [64:128) Sum cnt*g^2, [128:192) Sum g*DX,
//           [192:256) Sum g*DY, [256:320) Sum g*DZ
__global__ __launch_bounds__(256) void kB_g(const float* __restrict__ feat,
                                            const float* __restrict__ W1,
                                            const float* __restrict__ cnt,
                                            const float* __restrict__ DXa,
                                            const float* __restrict__ DYa,
                                            const float* __restrict__ DZa,
                                            float* __restrict__ g,
                                            float* __restrict__ A)
{
  __shared__ float red[320];
  for (int i = threadIdx.x; i < 320; i += 256) red[i] = 0.f;
  __syncthreads();
  const int lane = threadIdx.x & 63;
  const int gw = (blockIdx.x*256 + threadIdx.x) >> 6;
  float wf[DD];
  #pragma unroll
  for (int d = 0; d < DD; ++d) wf[d] = W1[(3+d)*CC1 + lane];
  float a1=0.f, a2=0.f, a3=0.f, a4=0.f, a5=0.f;
  for (int r = 0; r < 16; ++r) {
    int row = gw*16 + r;
    float f = feat[(size_t)row*DD + lane];
    float h0 = 0.f, h1 = 0.f, h2 = 0.f, h3 = 0.f;
    #pragma unroll
    for (int j = 0; j < 64; j += 4) {
      h0 = fmaf(rl(f, j  ), wf[j  ], h0);
      h1 = fmaf(rl(f, j+1), wf[j+1], h1);
      h2 = fmaf(rl(f, j+2), wf[j+2], h2);
      h3 = fmaf(rl(f, j+3), wf[j+3], h3);
    }
    float h = (h0+h1) + (h2+h3);
    g[(size_t)row*CC1 + lane] = h;
    float c = cnt[row], dxs = DXa[row], dys = DYa[row], dzs = DZa[row];
    float ch = c*h;
    a1 += ch; a2 = fmaf(ch, h, a2);
    a3 = fmaf(h, dxs, a3); a4 = fmaf(h, dys, a4); a5 = fmaf(h, dzs, a5);
  }
  atomicAdd(&red[lane], a1);
  atomicAdd(&red[64+lane], a2);
  atomicAdd(&red[128+lane], a3);
  atomicAdd(&red[192+lane], a4);
  atomicAdd(&red[256+lane], a5);
  __syncthreads();
  for (int i = threadIdx.x; i < 320; i += 256) unsafeAtomicAdd(&A[i], red[i]);
}

// ---------------- KS: assemble stats1 -> sc1, sh1, W1s ----------------
__global__ __launch_bounds__(256) void kS_fold(
    const float* __restrict__ W1, const float* __restrict__ gamma1,
    const float* __restrict__ beta1, const float* __restrict__ A,
    const float* __restrict__ mom,
    float* __restrict__ sc1, float* __restrict__ sh1, float* __restrict__ W1s)
{
  int c = threadIdx.x;
  if (c >= CC1) return;
  float wx = W1[c], wy = W1[CC1+c], wz = W1[2*CC1+c];
  float A1 = A[c], A2 = A[64+c], A3x = A[128+c], A3y = A[192+c], A3z = A[256+c];
  float sum1 = A1 + wx*mom[0] + wy*mom[1] + wz*mom[2];
  float ss = A2 + 2.f*(wx*A3x + wy*A3y + wz*A3z)
           + wx*wx*mom[3] + wy*wy*mom[4] + wz*wz*mom[5]
           + 2.f*(wx*wy*mom[6] + wx*wz*mom[7] + wy*wz*mom[8]);
  const float invN = 1.0f / (float)TOTROWS;
  float mean = sum1 * invN;
  float var  = ss * invN - mean*mean;
  float sc = rsqrtf(var + 1e-5f) * gamma1[c];
  float sh = beta1[c] - mean * sc;
  sc1[c] = sc; sh1[c] = sh;
  W1s[c] = wx*sc; W1s[64+c] = wy*sc; W1s[128+c] = wz*sc;
}

// ---------------- KD: MFMA main pass (BN1 inline) ----------------
// 1024 blocks -> 4096 waves x 4 sites. Per site A1(32x64 bf16) @ W2(64x128).
// a = relu(g*sc + dx*wxs + dy*wys + dz*wzs + sh).
// A-frag: lane holds A[m=lane&15][k=quad*8+j]; B-frag: B[k=quad*8+j][n=lane&15];
// C/D: col=lane&15, row=quad*4+reg (m89-verified).
__global__ __launch_bounds__(256, 2) void kD_mfma(
    const float* __restrict__ pos, const int* __restrict__ idx,
    const float* __restrict__ g, const float* __restrict__ sc1,
    const float* __restrict__ sh1, const float* __restrict__ W1s,
    const float* __restrict__ W2,
    float* __restrict__ stats2, float* __restrict__ out_nf)
{
  __shared__ float red2[256];
  red2[threadIdx.x] = 0.f;
  __syncthreads();
  const int lane = threadIdx.x & 63;
  const int quad = lane >> 4;
  const int col  = lane & 15;
  const int gw = (blockIdx.x*256 + threadIdx.x) >> 6;

  bf16x8 Bf[2][8];
  #pragma unroll
  for (int kt = 0; kt < 2; ++kt)
    #pragma unroll
    for (int nt = 0; nt < 8; ++nt) {
      bf16x8 v;
      #pragma unroll
      for (int j = 0; j < 8; ++j)
        v[j] = (__bf16)W2[(kt*32 + quad*8 + j)*CC2 + nt*16 + col];
      Bf[kt][nt] = v;
    }
  float wxs[2][8], wys[2][8], wzs[2][8], scj[2][8], shj[2][8];
  #pragma unroll
  for (int kt = 0; kt < 2; ++kt)
    #pragma unroll
    for (int j = 0; j < 8; ++j) {
      int c = kt*32 + quad*8 + j;
      wxs[kt][j] = W1s[c]; wys[kt][j] = W1s[64+c]; wzs[kt][j] = W1s[128+c];
      scj[kt][j] = sc1[c]; shj[kt][j] = sh1[c];
    }
  float ssum[8], ssq[8];
  #pragma unroll
  for (int nt = 0; nt < 8; ++nt) { ssum[nt] = 0.f; ssq[nt] = 0.f; }

  for (int si = 0; si < 4; ++si) {
    const int site = gw*4 + si;
    const int b = site >> 11;
    const float* pc = pos + (size_t)site*3;
    const float cx = pc[0], cy = pc[1], cz = pc[2];
    int mm[2]; float dx[2], dy[2], dz[2];
    #pragma unroll
    for (int mt = 0; mt < 2; ++mt) {
      mm[mt] = idx[site*KK + mt*16 + col];
      const float* pm = pos + ((size_t)b*NN + mm[mt])*3;
      dx[mt] = pm[0]-cx; dy[mt] = pm[1]-cy; dz[mt] = pm[2]-cz;
    }
    bf16x8 Af[2][2];
    #pragma unroll
    for (int mt = 0; mt < 2; ++mt)
      #pragma unroll
      for (int kt = 0; kt < 2; ++kt) {
        const float4* gp =
          (const float4*)(g + (((size_t)b*NN + mm[mt])*CC1 + kt*32 + quad*8));
        float4 g0 = gp[0], g1 = gp[1];
        float hv[8] = {g0.x,g0.y,g0.z,g0.w,g1.x,g1.y,g1.z,g1.w};
        bf16x8 v;
        #pragma unroll
        for (int j = 0; j < 8; ++j) {
          float t = fmaf(dz[mt], wzs[kt][j],
                    fmaf(dy[mt], wys[kt][j],
                    fmaf(dx[mt], wxs[kt][j], shj[kt][j])));
          float h = fmaf(hv[j], scj[kt][j], t);
          v[j] = (__bf16)fmaxf(h, 0.f);
        }
        Af[mt][kt] = v;
      }
    float mx[8];
    #pragma unroll
    for (int nt = 0; nt < 8; ++nt) mx[nt] = -3.0e38f;
    #pragma unroll
    for (int mt = 0; mt < 2; ++mt) {
      f32x4 acc[8];
      #pragma unroll
      for (int nt = 0; nt < 8; ++nt) {
        f32x4 a = {0.f, 0.f, 0.f, 0.f};
        a = __builtin_amdgcn_mfma_f32_16x16x32_bf16(Af[mt][0], Bf[0][nt], a, 0, 0, 0);
        a = __builtin_amdgcn_mfma_f32_16x16x32_bf16(Af[mt][1], Bf[1][nt], a, 0, 0, 0);
        acc[nt] = a;
      }
      #pragma unroll
      for (int nt = 0; nt < 8; ++nt)
        #pragma unroll
        for (int r = 0; r < 4; ++r) {
          float v = acc[nt][r];
          ssum[nt] += v; ssq[nt] = fmaf(v, v, ssq[nt]);
          mx[nt] = fmaxf(mx[nt], v);
        }
    }
    #pragma unroll
    for (int nt = 0; nt < 8; ++nt) {
      float m = mx[nt];
      m = fmaxf(m, __shfl_xor(m, 16, 64));
      m = fmaxf(m, __shfl_xor(m, 32, 64));
      if ((nt & 3) == quad)
        out_nf[(size_t)site*CC2 + nt*16 + col] = m;   // pre-BN pooled
    }
  }
  #pragma unroll
  for (int nt = 0; nt < 8; ++nt) {
    float s = ssum[nt];
    s += __shfl_xor(s, 16, 64); s += __shfl_xor(s, 32, 64);
    float q = ssq[nt];
    q += __shfl_xor(q, 16, 64); q += __shfl_xor(q, 32, 64);
    if (lane < 16) {
      atomicAdd(&red2[nt*16 + col], s);
      atomicAdd(&red2[128 + nt*16 + col], q);
    }
  }
  __syncthreads();
  unsafeAtomicAdd(&stats2[threadIdx.x], red2[threadIdx.x]);
}

// ---------------- K4: position pass-through ----------------
__global__ __launch_bounds__(256) void k4_pos(const float* __restrict__ pos,
                                              float* __restrict__ out) {
  int i = blockIdx.x*256 + threadIdx.x;
  out[i] = pos[i];
}

// ---------------- K5: bn2 + relu in place on pooled ----------------
__global__ __launch_bounds__(256) void k5_bn2(const float* __restrict__ g2,
                                              const float* __restrict__ be2,
                                              const float* __restrict__ stats2,
                                              float* __restrict__ out_nf) {
  int i = blockIdx.x*256 + threadIdx.x;
  int c = i & (CC2-1);
  const float invc = 1.0f / (float)TOTROWS;
  float mean = stats2[c] * invc;
  float var  = stats2[128 + c] * invc - mean*mean;
  float sc = rsqrtf(var + 1e-5f) * g2[c];
  float sh = be2[c] - mean * sc;
  float x = out_nf[i];
  out_nf[i] = fmaxf(fmaf(x, sc, sh), 0.f);
}

extern "C" void kernel_launch(void* const* d_in, const int* in_sizes, int n_in,
                              void* d_out, int out_size, void* d_ws, size_t ws_size,
                              hipStream_t stream) {
  const float* pos  = (const float*)d_in[0];
  const float* feat = (const float*)d_in[1];
  const float* W1   = (const float*)d_in[2];
  const float* g1   = (const float*)d_in[3];
  const float* be1  = (const float*)d_in[4];
  const float* W2   = (const float*)d_in[5];
  const float* g2   = (const float*)d_in[6];
  const float* be2  = (const float*)d_in[7];
  float* out = (float*)d_out;
  float* out_nf = out + (size_t)BB*NN*3;

  char* w = (char*)d_ws;
  int*   idx    = (int*)w;                   // 2 MB
  float* cnt    = (float*)(w + 0x200000);    // 16384
  float* DXa    = cnt + SITES;
  float* DYa    = DXa + SITES;
  float* DZa    = DYa + SITES;
  float* A      = DZa + SITES;               // 320
  float* mom    = A + 320;                   // 9 (pad to 16)
  float* stats2 = mom + 16;                  // 256
  float* sc1    = stats2 + 256;              // 64
  float* sh1    = sc1 + 64;                  // 64
  float* W1s    = sh1 + 64;                  // 192
  float* g      = (float*)(w + 0x200000 + 0x50000);  // 4 MB

  hipMemsetAsync(cnt, 0, (4*SITES + 320 + 16 + 256)*sizeof(float), stream);
  k1_ball   <<<512, 256, 0, stream>>>(pos, idx);
  kP_scatter<<<128, 256, 0, stream>>>(pos, idx, cnt, DXa, DYa, DZa, mom);
  kB_g      <<<256, 256, 0, stream>>>(feat, W1, cnt, DXa, DYa, DZa, g, A);
  kS_fold   <<<1, 256, 0, stream>>>(W1, g1, be1, A, mom, sc1, sh1, W1s);
  kD_mfma   <<<1024, 256, 0, stream>>>(pos, idx, g, sc1, sh1, W1s, W2,
                                       stats2, out_nf);
  k4_pos    <<<(BB*NN*3)/256, 256, 0, stream>>>(pos, out);
  k5_bn2    <<<(SITES*CC2)/256, 256, 0, stream>>>(g2, be2, stats2, out_nf);
}